// Round 3
// baseline (1375.907 us; speedup 1.0000x reference)
//
#include <hip/hip_runtime.h>
#include <math.h>

#define BB 4
#define TT 8
#define CC 128
#define HWW 9216            // 96*96
#define NPG 1179648.0f      // C*H*W per (b,t) group
#define EPS 1e-5f
#define SCALE 0.17677669529663687f   // 1/sqrt(32)

// ws layout in floats: sums[64] | A[32][128] | B[32][128]
#define WS_SUMS 0
#define WS_A    64
#define WS_B    4160

typedef __attribute__((ext_vector_type(4))) float f32x4;

// direct global->LDS, 16B per lane; HW writes lds_base + lane*16.
__device__ __forceinline__ void gload16(const float* g, float* l) {
    __builtin_amdgcn_global_load_lds(
        (const __attribute__((address_space(1))) void*)g,
        (__attribute__((address_space(3))) void*)l,
        16, 0, 0);
}

// stats: one block per (g, c) row. 4096 blocks x 256 threads, 9 float4/thread,
// perfectly sequential 36 KB per block -> deep independent load stream.
__global__ __launch_bounds__(256) void stats_kernel(
    const float* __restrict__ x, const float* __restrict__ pe,
    float* __restrict__ sums)
{
    const int bid = blockIdx.x;
    const int g = bid >> 7, c = bid & 127;
    const int t = g & 7;
    const int tid = threadIdx.x;
    const float pec = pe[t * CC + c];
    const float4* row = (const float4*)(x + ((size_t)g * CC + c) * HWW);
    float s1 = 0.f, s2 = 0.f;
    #pragma unroll
    for (int i = 0; i < 9; ++i) {           // 9*256 = 2304 float4 = 9216 floats
        float4 v = row[tid + i * 256];
        float a = v.x + pec, b = v.y + pec, cc2 = v.z + pec, d = v.w + pec;
        s1 += (a + b) + (cc2 + d);
        s2 += (a * a + b * b) + (cc2 * cc2 + d * d);
    }
    for (int off = 32; off; off >>= 1) {
        s1 += __shfl_down(s1, off);
        s2 += __shfl_down(s2, off);
    }
    __shared__ float red[8];
    const int wid = tid >> 6, lane = tid & 63;
    if (lane == 0) { red[wid] = s1; red[4 + wid] = s2; }
    __syncthreads();
    if (tid == 0) {
        atomicAdd(&sums[g * 2 + 0], red[0] + red[1] + red[2] + red[3]);
        atomicAdd(&sums[g * 2 + 1], red[4] + red[5] + red[6] + red[7]);
    }
}

__global__ void finalize_kernel(
    const float* __restrict__ pe, const float* __restrict__ nw,
    const float* __restrict__ nb, float* ws)
{
    const int g = blockIdx.x;
    const int c = threadIdx.x;
    const float inv = 1.0f / NPG;
    const float mean = ws[WS_SUMS + g * 2 + 0] * inv;
    const float var  = ws[WS_SUMS + g * 2 + 1] * inv - mean * mean;
    const float rstd = rsqrtf(var + EPS);
    const int t = g & 7;
    const float a = rstd * nw[c];
    ws[WS_A + g * CC + c] = a;
    ws[WS_B + g * CC + c] = (pe[t * CC + c] - mean) * a + nb[c];
}

// fused3: only the t=7 all-channel coupling uses an LDS tile. Scores and the
// xbar accumulation stream x DIRECTLY from global (per-lane coalesced, 256
// independent loads/thread, zero barriers inside the streams). 7 barriers
// total (vs 37 in fused2) — removes the per-tile vmcnt(0)+barrier drains that
// capped effective fetch BW at ~480 GB/s.
// 1024 threads = 16 waves, wave = (head n = w>>2, quarter hq = w&3), lane = pos.
__global__ __launch_bounds__(1024, 4) void fused3_kernel(
    const float* __restrict__ x, const float* __restrict__ ws,
    const float* __restrict__ qkv_w, const float* __restrict__ proj_w,
    float* __restrict__ out)
{
    __shared__ __align__(16) float smem0[CC * 64];  // xn7 tile -> score partials
    __shared__ __align__(16) float smem1[CC * 64];  // q7 exchange -> v accumulator

    const int tid  = threadIdx.x;
    const int lane = tid & 63;                  // position
    const int w    = tid >> 6;                  // wave 0..15
    const int wu   = __builtin_amdgcn_readfirstlane(w);
    const int n    = wu >> 2;                   // head
    const int hq   = wu & 3;                    // c-quarter
    const int b    = blockIdx.y;
    const int hw0  = blockIdx.x * 64;

    const float* A = ws + WS_A;
    const float* B = ws + WS_B;

    // ---- stage t=7 tile into smem0 (raw x; fold applied at read) ----
    {
        const int rsub = lane >> 4, coff = (lane & 15) * 4;
        const size_t gb = (size_t)((b * TT + 7) * CC) * HWW + hw0 + coff;
        #pragma unroll
        for (int k = 0; k < 2; ++k) {
            const int r0 = wu * 8 + k * 4;
            gload16(x + gb + (size_t)(r0 + rsub) * HWW, smem0 + r0 * 64);
        }
    }
    __syncthreads();

    // ---- q7 = Wq_n xn7 (8 d-rows per wave), exchange via smem1 ----
    const int g7 = b * TT + 7;
    const float* A7 = A + g7 * CC;
    const float* B7 = B + g7 * CC;
    {
        const float* Wq = qkv_w + (n * 32 + hq * 8) * CC;
        float q7[8] = {0.f,0.f,0.f,0.f,0.f,0.f,0.f,0.f};
        for (int c0 = 0; c0 < CC; c0 += 8) {
            float xv[8];
            #pragma unroll
            for (int i = 0; i < 8; ++i)
                xv[i] = fmaf(smem0[(c0 + i) * 64 + lane], A7[c0 + i], B7[c0 + i]);
            #pragma unroll
            for (int d = 0; d < 8; ++d) {
                #pragma unroll
                for (int i = 0; i < 8; ++i)
                    q7[d] = fmaf(Wq[d * CC + c0 + i], xv[i], q7[d]);
            }
        }
        #pragma unroll
        for (int d = 0; d < 8; ++d)
            smem1[(n * 32 + hq * 8 + d) * 64 + lane] = q7[d];
    }
    __syncthreads();

    // ---- u[32] = (Wk_n^T q7) slice hq*32..hq*32+31 ----
    float u[32];
    #pragma unroll
    for (int j = 0; j < 32; ++j) u[j] = 0.f;
    {
        const float* Wk = qkv_w + (CC + n * 32) * CC + hq * 32;
        for (int d = 0; d < 32; ++d) {
            const float qv = smem1[(n * 32 + d) * 64 + lane];
            #pragma unroll
            for (int j = 0; j < 32; ++j)
                u[j] = fmaf(Wk[d * CC + j], qv, u[j]);
        }
    }

    // ---- score streaming: ps[t] = sum_{j in slice} u[j]*xn_t[j][pos], direct
    //      global loads (lane-coalesced 256B per instr, no LDS, no barriers) ----
    float ps[8];
    #pragma unroll
    for (int t = 0; t < 8; ++t) {
        const float* Xt = x + ((size_t)((b * TT + t) * CC + hq * 32)) * HWW + hw0 + lane;
        const float* At = A + (b * TT + t) * CC + hq * 32;
        const float* Bt = B + (b * TT + t) * CC + hq * 32;
        float s0 = 0.f, s1 = 0.f, s2 = 0.f, s3 = 0.f;
        #pragma unroll
        for (int j = 0; j < 32; j += 4) {
            float v0 = fmaf(Xt[(size_t)(j + 0) * HWW], At[j + 0], Bt[j + 0]);
            float v1 = fmaf(Xt[(size_t)(j + 1) * HWW], At[j + 1], Bt[j + 1]);
            float v2 = fmaf(Xt[(size_t)(j + 2) * HWW], At[j + 2], Bt[j + 2]);
            float v3 = fmaf(Xt[(size_t)(j + 3) * HWW], At[j + 3], Bt[j + 3]);
            s0 = fmaf(u[j + 0], v0, s0);
            s1 = fmaf(u[j + 1], v1, s1);
            s2 = fmaf(u[j + 2], v2, s2);
            s3 = fmaf(u[j + 3], v3, s3);
        }
        ps[t] = (s0 + s1) + (s2 + s3);
    }

    // ---- cross-quarter reduce via smem0 (xn7 dead after q7 phase) ----
    #pragma unroll
    for (int t = 0; t < 8; ++t)
        smem0[(wu * 8 + t) * 64 + lane] = ps[t];
    __syncthreads();

    float wt[8];
    {
        float sreg[8];
        #pragma unroll
        for (int t = 0; t < 8; ++t)
            sreg[t] = (smem0[((n * 4 + 0) * 8 + t) * 64 + lane] +
                       smem0[((n * 4 + 1) * 8 + t) * 64 + lane]) +
                      (smem0[((n * 4 + 2) * 8 + t) * 64 + lane] +
                       smem0[((n * 4 + 3) * 8 + t) * 64 + lane]);
        float m = fmaxf(fmaxf(fmaxf(sreg[0], sreg[1]), fmaxf(sreg[2], sreg[3])),
                        fmaxf(fmaxf(sreg[4], sreg[5]), fmaxf(sreg[6], sreg[7])));
        float l = 0.f;
        #pragma unroll
        for (int t = 0; t < 8; ++t) { wt[t] = __expf((sreg[t] - m) * SCALE); l += wt[t]; }
        const float invl = 1.0f / l;
        #pragma unroll
        for (int t = 0; t < 8; ++t) wt[t] *= invl;
    }

    // ---- pass 2 streaming: xb[32] = sum_t wt[t]*xn_t[slice][pos], direct global ----
    float xb[32];
    #pragma unroll
    for (int j = 0; j < 32; ++j) xb[j] = 0.f;
    #pragma unroll
    for (int t = 0; t < 8; ++t) {
        const float* Xt = x + ((size_t)((b * TT + t) * CC + hq * 32)) * HWW + hw0 + lane;
        const float* At = A + (b * TT + t) * CC + hq * 32;
        const float* Bt = B + (b * TT + t) * CC + hq * 32;
        const float wc = wt[t];
        #pragma unroll
        for (int j = 0; j < 32; ++j) {
            float xv = fmaf(Xt[(size_t)j * HWW], At[j], Bt[j]);
            xb[j] = fmaf(xv, wc, xb[j]);
        }
    }

    // ---- v_n[d] = Wv_n xbar_n: quarter partials reduced into smem1 (q7 dead;
    //      all u-phase reads completed before the psbuf barrier) ----
    {
        const float* Wv = qkv_w + (2 * CC + n * 32) * CC + hq * 32;
        #pragma unroll
        for (int r = 0; r < 4; ++r) {
            if (hq == r) {            // wave-uniform
                for (int d0 = 0; d0 < 32; d0 += 8) {
                    float vp[8];
                    #pragma unroll
                    for (int d = 0; d < 8; ++d) {
                        float s0 = 0.f, s1 = 0.f, s2 = 0.f, s3 = 0.f;
                        const float* Wr = Wv + (d0 + d) * CC;
                        #pragma unroll
                        for (int c = 0; c < 32; c += 4) {
                            s0 = fmaf(Wr[c + 0], xb[c + 0], s0);
                            s1 = fmaf(Wr[c + 1], xb[c + 1], s1);
                            s2 = fmaf(Wr[c + 2], xb[c + 2], s2);
                            s3 = fmaf(Wr[c + 3], xb[c + 3], s3);
                        }
                        vp[d] = (s0 + s1) + (s2 + s3);
                    }
                    if (r == 0) {
                        #pragma unroll
                        for (int d = 0; d < 8; ++d)
                            smem1[(n * 32 + d0 + d) * 64 + lane] = vp[d];
                    } else {
                        #pragma unroll
                        for (int d = 0; d < 8; ++d)
                            smem1[(n * 32 + d0 + d) * 64 + lane] += vp[d];
                    }
                }
            }
            __syncthreads();
        }
    }

    // ---- y[e] = sum_c P[e][c] v[c], e-slice per wave, scalar P loads ----
    float y[8];
    #pragma unroll
    for (int e = 0; e < 8; ++e) y[e] = 0.f;
    for (int c0 = 0; c0 < CC; c0 += 16) {
        float vv[16];
        #pragma unroll
        for (int i = 0; i < 16; ++i) vv[i] = smem1[(c0 + i) * 64 + lane];
        #pragma unroll
        for (int e = 0; e < 8; ++e) {
            const float* Pr = proj_w + (wu * 8 + e) * CC + c0;   // wu: SGPR base
            #pragma unroll
            for (int i = 0; i < 16; ++i)
                y[e] = fmaf(Pr[i], vv[i], y[e]);
        }
    }
    const size_t ob = (size_t)(b * CC + wu * 8) * HWW + hw0 + lane;
    #pragma unroll
    for (int e = 0; e < 8; ++e)
        out[ob + (size_t)e * HWW] = y[e];
}

extern "C" void kernel_launch(void* const* d_in, const int* in_sizes, int n_in,
                              void* d_out, int out_size, void* d_ws, size_t ws_size,
                              hipStream_t stream) {
    const float* x      = (const float*)d_in[0];
    const float* pe     = (const float*)d_in[1];
    const float* nw     = (const float*)d_in[2];
    const float* nb     = (const float*)d_in[3];
    const float* qkv_w  = (const float*)d_in[4];
    const float* proj_w = (const float*)d_in[5];
    float* out = (float*)d_out;
    float* ws  = (float*)d_ws;

    hipMemsetAsync(ws, 0, 64 * sizeof(float), stream);
    stats_kernel<<<4096, 256, 0, stream>>>(x, pe, ws);
    finalize_kernel<<<32, 128, 0, stream>>>(pe, nw, nb, ws);
    fused3_kernel<<<dim3(HWW / 64, BB), 1024, 0, stream>>>(x, ws, qkv_w, proj_w, out);
}

// Round 5
// 544.628 us; speedup vs baseline: 2.5263x; 2.5263x over previous
//
#include <hip/hip_runtime.h>
#include <math.h>

#define BB 4
#define TT 8
#define CC 128
#define HWW 9216            // 96*96
#define NPG 1179648.0f      // C*H*W per (b,t) group
#define EPS 1e-5f
#define SCALE 0.17677669529663687f   // 1/sqrt(32)

// ws layout in floats: sums[64] | A[32][128] | B[32][128]
#define WS_SUMS 0
#define WS_A    64
#define WS_B    4160

typedef __attribute__((ext_vector_type(4))) float f32x4;

// direct global->LDS, 16B per lane; HW writes lds_base + lane*16.
__device__ __forceinline__ void gload16(const float* g, float* l) {
    __builtin_amdgcn_global_load_lds(
        (const __attribute__((address_space(1))) void*)g,
        (__attribute__((address_space(3))) void*)l,
        16, 0, 0);
}

// stats: one block per (g, c) row. 4096 blocks x 256 threads, 9 float4/thread,
// perfectly sequential 36 KB per block (verified correct+fast in R3).
__global__ __launch_bounds__(256) void stats_kernel(
    const float* __restrict__ x, const float* __restrict__ pe,
    float* __restrict__ sums)
{
    const int bid = blockIdx.x;
    const int g = bid >> 7, c = bid & 127;
    const int t = g & 7;
    const int tid = threadIdx.x;
    const float pec = pe[t * CC + c];
    const float4* row = (const float4*)(x + ((size_t)g * CC + c) * HWW);
    float s1 = 0.f, s2 = 0.f;
    #pragma unroll
    for (int i = 0; i < 9; ++i) {
        float4 v = row[tid + i * 256];
        float a = v.x + pec, b = v.y + pec, cc2 = v.z + pec, d = v.w + pec;
        s1 += (a + b) + (cc2 + d);
        s2 += (a * a + b * b) + (cc2 * cc2 + d * d);
    }
    for (int off = 32; off; off >>= 1) {
        s1 += __shfl_down(s1, off);
        s2 += __shfl_down(s2, off);
    }
    __shared__ float red[8];
    const int wid = tid >> 6, lane = tid & 63;
    if (lane == 0) { red[wid] = s1; red[4 + wid] = s2; }
    __syncthreads();
    if (tid == 0) {
        atomicAdd(&sums[g * 2 + 0], red[0] + red[1] + red[2] + red[3]);
        atomicAdd(&sums[g * 2 + 1], red[4] + red[5] + red[6] + red[7]);
    }
}

__global__ void finalize_kernel(
    const float* __restrict__ pe, const float* __restrict__ nw,
    const float* __restrict__ nb, float* ws)
{
    const int g = blockIdx.x;
    const int c = threadIdx.x;
    const float inv = 1.0f / NPG;
    const float mean = ws[WS_SUMS + g * 2 + 0] * inv;
    const float var  = ws[WS_SUMS + g * 2 + 1] * inv - mean * mean;
    const float rstd = rsqrtf(var + EPS);
    const int t = g & 7;
    const float a = rstd * nw[c];
    ws[WS_A + g * CC + c] = a;
    ws[WS_B + g * CC + c] = (pe[t * CC + c] - mean) * a + nb[c];
}

// fused5: single-pass online-softmax (8 tiles staged, not R2's 16) with
// double-buffered prefetch, but ALL barriers are plain __syncthreads() —
// the raw split-waitcnt barrier variants (R1/R4) killed the container and
// are undebuggable blind. stage(t+1) is issued right after the top barrier
// so score_partial covers part of its latency before the sbuf-exchange
// barrier drains vmcnt.
// 1024 threads = 16 waves, wave = (head n = w>>2, quarter hq = w&3), lane = pos.
// LDS: bufA(32K) + bufB(32K) + sbuf(4K). q7-exchange overlays bufB (before
// t=0 is staged); v-accumulator overlays bufA (after the loop).
__global__ __launch_bounds__(1024, 4) void fused5_kernel(
    const float* __restrict__ x, const float* __restrict__ ws,
    const float* __restrict__ qkv_w, const float* __restrict__ proj_w,
    float* __restrict__ out)
{
    __shared__ __align__(16) float bufA[CC * 64];
    __shared__ __align__(16) float bufB[CC * 64];
    __shared__ float sbuf[16 * 64];

    const int tid  = threadIdx.x;
    const int lane = tid & 63;                  // position
    const int w    = tid >> 6;                  // wave 0..15
    const int wu   = __builtin_amdgcn_readfirstlane(w);
    const int n    = wu >> 2;                   // head
    const int hq   = wu & 3;                    // c-quarter
    const int b    = blockIdx.y;
    const int hw0  = blockIdx.x * 64;

    const float* A = ws + WS_A;
    const float* B = ws + WS_B;

    const int rsub = lane >> 4, coff = (lane & 15) * 4;

    // stage tile t into dst: wave w loads rows wu*8..wu*8+7 (2 x gload16)
    auto stage = [&](int t, float* dst) {
        const size_t gb = (size_t)((b * TT + t) * CC) * HWW + hw0 + coff;
        #pragma unroll
        for (int k = 0; k < 2; ++k) {
            const int r0 = wu * 8 + k * 4;
            gload16(x + gb + (size_t)(r0 + rsub) * HWW, dst + r0 * 64);
        }
    };

    float u[32];
    // quarter-score partial for tile in buf: sum_j u[j] * xn[hq*32+j][lane]
    auto score_partial = [&](const float* buf, const float* At, const float* Bt) {
        float s0 = 0.f, s1 = 0.f, s2 = 0.f, s3 = 0.f;
        #pragma unroll
        for (int j = 0; j < 32; j += 4) {
            float x0 = fmaf(buf[(hq * 32 + j + 0) * 64 + lane], At[j + 0], Bt[j + 0]);
            float x1 = fmaf(buf[(hq * 32 + j + 1) * 64 + lane], At[j + 1], Bt[j + 1]);
            float x2 = fmaf(buf[(hq * 32 + j + 2) * 64 + lane], At[j + 2], Bt[j + 2]);
            float x3 = fmaf(buf[(hq * 32 + j + 3) * 64 + lane], At[j + 3], Bt[j + 3]);
            s0 = fmaf(u[j + 0], x0, s0);
            s1 = fmaf(u[j + 1], x1, s1);
            s2 = fmaf(u[j + 2], x2, s2);
            s3 = fmaf(u[j + 3], x3, s3);
        }
        return (s0 + s1) + (s2 + s3);
    };

    // ---- prologue: stage t=7 into bufA ----
    stage(7, bufA);
    __syncthreads();

    // ---- q7 = Wq_n xn7 (8 d-rows per wave) from bufA, exchange via bufB ----
    const int g7 = b * TT + 7;
    const float* A7 = A + g7 * CC;
    const float* B7 = B + g7 * CC;
    {
        const float* Wq = qkv_w + (n * 32 + hq * 8) * CC;
        float q7[8] = {0.f,0.f,0.f,0.f,0.f,0.f,0.f,0.f};
        for (int c0 = 0; c0 < CC; c0 += 8) {
            float xv[8];
            #pragma unroll
            for (int i = 0; i < 8; ++i)
                xv[i] = fmaf(bufA[(c0 + i) * 64 + lane], A7[c0 + i], B7[c0 + i]);
            #pragma unroll
            for (int d = 0; d < 8; ++d) {
                #pragma unroll
                for (int i = 0; i < 8; ++i)
                    q7[d] = fmaf(Wq[d * CC + c0 + i], xv[i], q7[d]);
            }
        }
        #pragma unroll
        for (int d = 0; d < 8; ++d)
            bufB[(n * 32 + hq * 8 + d) * 64 + lane] = q7[d];
    }
    __syncthreads();                 // q7 visible in bufB

    // ---- u[32] = (Wk_n^T q7) slice hq*32.. from bufB ----
    #pragma unroll
    for (int j = 0; j < 32; ++j) u[j] = 0.f;
    {
        const float* Wk = qkv_w + (CC + n * 32) * CC + hq * 32;
        for (int d = 0; d < 32; ++d) {
            const float qv = bufB[(n * 32 + d) * 64 + lane];
            #pragma unroll
            for (int j = 0; j < 32; ++j)
                u[j] = fmaf(Wk[d * CC + j], qv, u[j]);
        }
    }
    __syncthreads();                 // all waves done reading bufB (q7)

    stage(0, bufB);                  // t=0 loads issued; partially covered by
                                     // t7 score below

    // ---- t=7 score from bufA, init online state ----
    sbuf[w * 64 + lane] = score_partial(bufA, A7 + hq * 32, B7 + hq * 32);
    __syncthreads();                 // sbuf ready (also drains stage(0))
    float sc = (sbuf[(n * 4 + 0) * 64 + lane] + sbuf[(n * 4 + 1) * 64 + lane]) +
               (sbuf[(n * 4 + 2) * 64 + lane] + sbuf[(n * 4 + 3) * 64 + lane]);
    float m = sc, l = 1.f;
    float xb[32];
    #pragma unroll
    for (int j = 0; j < 32; ++j)
        xb[j] = fmaf(bufA[(hq * 32 + j) * 64 + lane],
                     A7[hq * 32 + j], B7[hq * 32 + j]);

    // ---- main loop t=0..6: dbuf, 2 __syncthreads per tile ----
    #pragma unroll
    for (int t = 0; t < 7; ++t) {
        float* cur = (t & 1) ? bufA : bufB;      // t0->B, t1->A, ...
        float* oth = (t & 1) ? bufB : bufA;
        __syncthreads();             // all reads of oth done (tile t already drained)
        if (t < 6) stage(t + 1, oth);            // issue next tile now
        const float* At = A + (b * TT + t) * CC + hq * 32;
        const float* Bt = B + (b * TT + t) * CC + hq * 32;
        sbuf[w * 64 + lane] = score_partial(cur, At, Bt);
        __syncthreads();             // sbuf ready (drains stage(t+1) as side effect)
        sc = (sbuf[(n * 4 + 0) * 64 + lane] + sbuf[(n * 4 + 1) * 64 + lane]) +
             (sbuf[(n * 4 + 2) * 64 + lane] + sbuf[(n * 4 + 3) * 64 + lane]);
        const float mnew  = fmaxf(m, sc);
        const float alpha = __expf((m - mnew) * SCALE);
        const float e     = __expf((sc - mnew) * SCALE);
        l = l * alpha + e;
        m = mnew;
        #pragma unroll
        for (int j = 0; j < 32; ++j) {
            float xv = fmaf(cur[(hq * 32 + j) * 64 + lane], At[j], Bt[j]);
            xb[j] = fmaf(xv, e, xb[j] * alpha);
        }
    }

    const float invl = 1.0f / l;
    #pragma unroll
    for (int j = 0; j < 32; ++j) xb[j] *= invl;

    __syncthreads();                 // all tile reads done; bufA free for v

    // ---- v_n[d] = Wv_n xbar_n: quarter partials reduced into bufA ----
    {
        const float* Wv = qkv_w + (2 * CC + n * 32) * CC + hq * 32;
        #pragma unroll
        for (int r = 0; r < 4; ++r) {
            if (hq == r) {           // wave-uniform
                for (int d0 = 0; d0 < 32; d0 += 8) {
                    float vp[8];
                    #pragma unroll
                    for (int d = 0; d < 8; ++d) {
                        float s0 = 0.f, s1 = 0.f, s2 = 0.f, s3 = 0.f;
                        const float* Wr = Wv + (d0 + d) * CC;
                        #pragma unroll
                        for (int c = 0; c < 32; c += 4) {
                            s0 = fmaf(Wr[c + 0], xb[c + 0], s0);
                            s1 = fmaf(Wr[c + 1], xb[c + 1], s1);
                            s2 = fmaf(Wr[c + 2], xb[c + 2], s2);
                            s3 = fmaf(Wr[c + 3], xb[c + 3], s3);
                        }
                        vp[d] = (s0 + s1) + (s2 + s3);
                    }
                    if (r == 0) {
                        #pragma unroll
                        for (int d = 0; d < 8; ++d)
                            bufA[(n * 32 + d0 + d) * 64 + lane] = vp[d];
                    } else {
                        #pragma unroll
                        for (int d = 0; d < 8; ++d)
                            bufA[(n * 32 + d0 + d) * 64 + lane] += vp[d];
                    }
                }
            }
            __syncthreads();
        }
    }

    // ---- y[e] = sum_c P[e][c] v[c], e-slice per wave, scalar P loads ----
    float y[8];
    #pragma unroll
    for (int e = 0; e < 8; ++e) y[e] = 0.f;
    for (int c0 = 0; c0 < CC; c0 += 16) {
        float vv[16];
        #pragma unroll
        for (int i = 0; i < 16; ++i) vv[i] = bufA[(c0 + i) * 64 + lane];
        #pragma unroll
        for (int e = 0; e < 8; ++e) {
            const float* Pr = proj_w + (wu * 8 + e) * CC + c0;   // SGPR base
            #pragma unroll
            for (int i = 0; i < 16; ++i)
                y[e] = fmaf(Pr[i], vv[i], y[e]);
        }
    }
    const size_t ob = (size_t)(b * CC + wu * 8) * HWW + hw0 + lane;
    #pragma unroll
    for (int e = 0; e < 8; ++e)
        out[ob + (size_t)e * HWW] = y[e];
}

extern "C" void kernel_launch(void* const* d_in, const int* in_sizes, int n_in,
                              void* d_out, int out_size, void* d_ws, size_t ws_size,
                              hipStream_t stream) {
    const float* x      = (const float*)d_in[0];
    const float* pe     = (const float*)d_in[1];
    const float* nw     = (const float*)d_in[2];
    const float* nb     = (const float*)d_in[3];
    const float* qkv_w  = (const float*)d_in[4];
    const float* proj_w = (const float*)d_in[5];
    float* out = (float*)d_out;
    float* ws  = (float*)d_ws;

    hipMemsetAsync(ws, 0, 64 * sizeof(float), stream);
    stats_kernel<<<4096, 256, 0, stream>>>(x, pe, ws);
    finalize_kernel<<<32, 128, 0, stream>>>(pe, nw, nb, ws);
    fused5_kernel<<<dim3(HWW / 64, BB), 1024, 0, stream>>>(x, ws, qkv_w, proj_w, out);
}

// Round 6
// 471.638 us; speedup vs baseline: 2.9173x; 1.1548x over previous
//
#include <hip/hip_runtime.h>
#include <math.h>

#define BB 4
#define TT 8
#define CC 128
#define HWW 9216            // 96*96
#define NPG 1179648.0f      // C*H*W per (b,t) group
#define EPS 1e-5f
#define SCALE 0.17677669529663687f   // 1/sqrt(32)

// ws layout in floats: part[4096*2] | A[32][128] | B[32][128]
#define WS_PART 0
#define WS_A    8192
#define WS_B    12288

typedef __attribute__((ext_vector_type(4))) float f32x4;

// direct global->LDS, 16B per lane; HW writes lds_base + lane*16.
__device__ __forceinline__ void gload16(const float* g, float* l) {
    __builtin_amdgcn_global_load_lds(
        (const __attribute__((address_space(1))) void*)g,
        (__attribute__((address_space(3))) void*)l,
        16, 0, 0);
}

// stats v2: one block per (g, c) row; NON-ATOMIC per-block partial stores.
// (R0..R5 used 8192 atomicAdds onto 64 floats = 4 cache lines, cross-XCD —
// suspected ~200 us of device-serialized atomics, the constant total-vs-fused gap.)
__global__ __launch_bounds__(256) void stats_kernel(
    const float* __restrict__ x, const float* __restrict__ pe,
    float* __restrict__ part)
{
    const int bid = blockIdx.x;              // 4096 = 32 g x 128 c
    const int g = bid >> 7, c = bid & 127;
    const int t = g & 7;
    const int tid = threadIdx.x;
    const float pec = pe[t * CC + c];
    const float4* row = (const float4*)(x + ((size_t)g * CC + c) * HWW);
    float s1 = 0.f, s2 = 0.f;
    #pragma unroll
    for (int i = 0; i < 9; ++i) {            // 9*256 = 2304 float4 = 9216 floats
        float4 v = row[tid + i * 256];
        float a = v.x + pec, b = v.y + pec, cc2 = v.z + pec, d = v.w + pec;
        s1 += (a + b) + (cc2 + d);
        s2 += (a * a + b * b) + (cc2 * cc2 + d * d);
    }
    for (int off = 32; off; off >>= 1) {
        s1 += __shfl_down(s1, off);
        s2 += __shfl_down(s2, off);
    }
    __shared__ float red[8];
    const int wid = tid >> 6, lane = tid & 63;
    if (lane == 0) { red[wid] = s1; red[4 + wid] = s2; }
    __syncthreads();
    if (tid == 0) {
        part[bid * 2 + 0] = red[0] + red[1] + red[2] + red[3];
        part[bid * 2 + 1] = red[4] + red[5] + red[6] + red[7];
    }
}

// finalize v2: block g reduces its 128 c-partials (no atomics anywhere).
__global__ __launch_bounds__(128) void finalize_kernel(
    const float* __restrict__ pe, const float* __restrict__ nw,
    const float* __restrict__ nb, float* ws)
{
    const int g = blockIdx.x;
    const int c = threadIdx.x;               // 0..127
    const float* part = ws + WS_PART + g * 256;
    float s1 = part[c * 2 + 0];
    float s2 = part[c * 2 + 1];
    for (int off = 32; off; off >>= 1) {
        s1 += __shfl_down(s1, off);
        s2 += __shfl_down(s2, off);
    }
    __shared__ float r[4];
    const int wid = c >> 6, lane = c & 63;
    if (lane == 0) { r[wid] = s1; r[2 + wid] = s2; }
    __syncthreads();
    const float inv = 1.0f / NPG;
    const float mean = (r[0] + r[1]) * inv;
    const float var  = (r[2] + r[3]) * inv - mean * mean;
    const float rstd = rsqrtf(var + EPS);
    const int t = g & 7;
    const float a = rstd * nw[c];
    ws[WS_A + g * CC + c] = a;
    ws[WS_B + g * CC + c] = (pe[t * CC + c] - mean) * a + nb[c];
}

// fused6: deferred-softmax two-phase version of fused5.
//  phase A: ps[0..7] quarter-scores in regs (1 bar/tile, dbuf prefetch)
//  one exchange (ps -> bufA) + exact softmax -> wt[8]
//  phase B: re-stream 8 tiles (LLC-hot per R2 FETCH evidence), xb += wt*xn
//  v: all-wave quarter partials + pairwise tree merge via bufA/bufB (no idle waves)
//  y: y[e] = sum_c P[e][c]*(v01[c]+v23[c]) from both buffers.
// 1024 threads = 16 waves, wave = (head n = w>>2, quarter hq = w&3), lane = pos.
// All barriers are plain __syncthreads(). LDS = 64 KB (2 buffers, no sbuf).
__global__ __launch_bounds__(1024, 4) void fused6_kernel(
    const float* __restrict__ x, const float* __restrict__ ws,
    const float* __restrict__ qkv_w, const float* __restrict__ proj_w,
    float* __restrict__ out)
{
    __shared__ __align__(16) float bufA[CC * 64];
    __shared__ __align__(16) float bufB[CC * 64];

    const int tid  = threadIdx.x;
    const int lane = tid & 63;                  // position
    const int w    = tid >> 6;                  // wave 0..15
    const int wu   = __builtin_amdgcn_readfirstlane(w);
    const int n    = wu >> 2;                   // head
    const int hq   = wu & 3;                    // c-quarter
    const int b    = blockIdx.y;
    const int hw0  = blockIdx.x * 64;

    const float* A = ws + WS_A;
    const float* B = ws + WS_B;

    const int rsub = lane >> 4, coff = (lane & 15) * 4;

    // stage tile t into dst: wave w loads rows wu*8..wu*8+7 (2 x gload16)
    auto stage = [&](int t, float* dst) {
        const size_t gb = (size_t)((b * TT + t) * CC) * HWW + hw0 + coff;
        #pragma unroll
        for (int k = 0; k < 2; ++k) {
            const int r0 = wu * 8 + k * 4;
            gload16(x + gb + (size_t)(r0 + rsub) * HWW, dst + r0 * 64);
        }
    };

    float u[32];
    // quarter-score partial: sum_j u[j] * fold(xn[hq*32+j][lane])
    auto score_partial = [&](const float* buf, const float* At, const float* Bt) {
        float s0 = 0.f, s1 = 0.f, s2 = 0.f, s3 = 0.f;
        #pragma unroll
        for (int j = 0; j < 32; j += 4) {
            float x0 = fmaf(buf[(hq * 32 + j + 0) * 64 + lane], At[j + 0], Bt[j + 0]);
            float x1 = fmaf(buf[(hq * 32 + j + 1) * 64 + lane], At[j + 1], Bt[j + 1]);
            float x2 = fmaf(buf[(hq * 32 + j + 2) * 64 + lane], At[j + 2], Bt[j + 2]);
            float x3 = fmaf(buf[(hq * 32 + j + 3) * 64 + lane], At[j + 3], Bt[j + 3]);
            s0 = fmaf(u[j + 0], x0, s0);
            s1 = fmaf(u[j + 1], x1, s1);
            s2 = fmaf(u[j + 2], x2, s2);
            s3 = fmaf(u[j + 3], x3, s3);
        }
        return (s0 + s1) + (s2 + s3);
    };

    // ---- prologue: stage t=7 ----
    stage(7, bufA);
    __syncthreads();                           // tile7 ready

    // ---- q7 = Wq_n xn7 (8 full d-rows per wave) -> bufB ----
    const int g7 = b * TT + 7;
    const float* A7 = A + g7 * CC;
    const float* B7 = B + g7 * CC;
    {
        const float* Wq = qkv_w + (n * 32 + hq * 8) * CC;
        float q7[8] = {0.f,0.f,0.f,0.f,0.f,0.f,0.f,0.f};
        for (int c0 = 0; c0 < CC; c0 += 8) {
            float xv[8];
            #pragma unroll
            for (int i = 0; i < 8; ++i)
                xv[i] = fmaf(bufA[(c0 + i) * 64 + lane], A7[c0 + i], B7[c0 + i]);
            #pragma unroll
            for (int d = 0; d < 8; ++d) {
                #pragma unroll
                for (int i = 0; i < 8; ++i)
                    q7[d] = fmaf(Wq[d * CC + c0 + i], xv[i], q7[d]);
            }
        }
        #pragma unroll
        for (int d = 0; d < 8; ++d)
            bufB[(n * 32 + hq * 8 + d) * 64 + lane] = q7[d];
    }
    __syncthreads();                           // q7 visible

    // ---- u[32] = (Wk_n^T q7) slice hq*32.. ----
    #pragma unroll
    for (int j = 0; j < 32; ++j) u[j] = 0.f;
    {
        const float* Wk = qkv_w + (CC + n * 32) * CC + hq * 32;
        for (int d = 0; d < 32; ++d) {
            const float qv = bufB[(n * 32 + d) * 64 + lane];
            #pragma unroll
            for (int j = 0; j < 32; ++j)
                u[j] = fmaf(Wk[d * CC + j], qv, u[j]);
        }
    }
    __syncthreads();                           // q7 reads done; bufB free

    // ---- phase A: all 8 quarter-scores into regs, 1 bar/tile ----
    float ps[8];
    stage(0, bufB);
    ps[7] = score_partial(bufA, A7 + hq * 32, B7 + hq * 32);
    __syncthreads();                           // t0 ready; tile7 reads done
    #pragma unroll
    for (int t = 0; t < 7; ++t) {
        const float* cur = (t & 1) ? bufA : bufB;
        float* oth = (t & 1) ? bufB : bufA;
        if (t < 6) stage(t + 1, oth);
        const float* At = A + (b * TT + t) * CC + hq * 32;
        const float* Bt = B + (b * TT + t) * CC + hq * 32;
        ps[t] = score_partial(cur, At, Bt);
        __syncthreads();                       // next tile ready; cur reads done
    }

    // ---- single exchange + exact softmax ----
    stage(0, bufB);                            // phase-B t0 prefetch (bufB free: ps6 done)
    #pragma unroll
    for (int t = 0; t < 8; ++t)
        bufA[(wu * 8 + t) * 64 + lane] = ps[t];    // bufA free: last tile read was t5
    __syncthreads();                           // exchange visible (stage(0) drained too)

    float wt[8];
    {
        float sreg[8];
        #pragma unroll
        for (int t = 0; t < 8; ++t)
            sreg[t] = (bufA[((n * 4 + 0) * 8 + t) * 64 + lane] +
                       bufA[((n * 4 + 1) * 8 + t) * 64 + lane]) +
                      (bufA[((n * 4 + 2) * 8 + t) * 64 + lane] +
                       bufA[((n * 4 + 3) * 8 + t) * 64 + lane]);
        float m = fmaxf(fmaxf(fmaxf(sreg[0], sreg[1]), fmaxf(sreg[2], sreg[3])),
                        fmaxf(fmaxf(sreg[4], sreg[5]), fmaxf(sreg[6], sreg[7])));
        float l = 0.f;
        #pragma unroll
        for (int t = 0; t < 8; ++t) { wt[t] = __expf((sreg[t] - m) * SCALE); l += wt[t]; }
        const float invl = 1.0f / l;
        #pragma unroll
        for (int t = 0; t < 8; ++t) wt[t] *= invl;
    }
    __syncthreads();                           // sreg reads done; bufA free

    // ---- phase B: re-stream 8 tiles (LLC-hot), xb += wt*fold ----
    float xb[32];
    #pragma unroll
    for (int j = 0; j < 32; ++j) xb[j] = 0.f;
    #pragma unroll
    for (int t = 0; t < 8; ++t) {
        const float* cur = (t & 1) ? bufA : bufB;
        float* oth = (t & 1) ? bufB : bufA;
        if (t < 7) stage(t + 1, oth);
        const float* At = A + (b * TT + t) * CC + hq * 32;
        const float* Bt = B + (b * TT + t) * CC + hq * 32;
        const float wc = wt[t];
        #pragma unroll
        for (int j = 0; j < 32; ++j) {
            float xv = fmaf(cur[(hq * 32 + j) * 64 + lane], At[j], Bt[j]);
            xb[j] = fmaf(xv, wc, xb[j]);
        }
        __syncthreads();                       // next tile ready; cur reads done
    }

    // ---- v: all waves compute quarter partials; pairwise tree via buffers ----
    // v01 (hq0+hq1) accumulates in bufB rows [n*32+d]; v23 in bufA rows.
    {
        const float* Wv = qkv_w + (2 * CC + n * 32) * CC + hq * 32;
        float vprev[8];
        #pragma unroll
        for (int gi = 0; gi < 4; ++gi) {
            float vp[8];
            #pragma unroll
            for (int d = 0; d < 8; ++d) {
                float s0 = 0.f, s1 = 0.f, s2 = 0.f, s3 = 0.f;
                const float* Wr = Wv + (gi * 8 + d) * CC;
                #pragma unroll
                for (int c = 0; c < 32; c += 4) {
                    s0 = fmaf(Wr[c + 0], xb[c + 0], s0);
                    s1 = fmaf(Wr[c + 1], xb[c + 1], s1);
                    s2 = fmaf(Wr[c + 2], xb[c + 2], s2);
                    s3 = fmaf(Wr[c + 3], xb[c + 3], s3);
                }
                vp[d] = (s0 + s1) + (s2 + s3);
            }
            if (hq == 1) {
                #pragma unroll
                for (int d = 0; d < 8; ++d)
                    bufB[(n * 32 + gi * 8 + d) * 64 + lane] = vp[d];
            }
            if (hq == 3) {
                #pragma unroll
                for (int d = 0; d < 8; ++d)
                    bufA[(n * 32 + gi * 8 + d) * 64 + lane] = vp[d];
            }
            if (gi > 0) {                      // merge previous group
                if (hq == 0) {
                    #pragma unroll
                    for (int d = 0; d < 8; ++d) {
                        const int r = (n * 32 + (gi - 1) * 8 + d) * 64 + lane;
                        bufB[r] += vprev[d];
                    }
                }
                if (hq == 2) {
                    #pragma unroll
                    for (int d = 0; d < 8; ++d) {
                        const int r = (n * 32 + (gi - 1) * 8 + d) * 64 + lane;
                        bufA[r] += vprev[d];
                    }
                }
            }
            #pragma unroll
            for (int d = 0; d < 8; ++d) vprev[d] = vp[d];
            __syncthreads();
        }
        if (hq == 0) {
            #pragma unroll
            for (int d = 0; d < 8; ++d)
                bufB[(n * 32 + 24 + d) * 64 + lane] += vprev[d];
        }
        if (hq == 2) {
            #pragma unroll
            for (int d = 0; d < 8; ++d)
                bufA[(n * 32 + 24 + d) * 64 + lane] += vprev[d];
        }
    }
    __syncthreads();                           // v01/v23 complete

    // ---- y[e] = sum_c P[e][c] * (v01[c]+v23[c]), e-slice per wave ----
    float y[8];
    #pragma unroll
    for (int e = 0; e < 8; ++e) y[e] = 0.f;
    for (int c0 = 0; c0 < CC; c0 += 16) {
        float vv[16];
        #pragma unroll
        for (int i = 0; i < 16; ++i)
            vv[i] = bufB[(c0 + i) * 64 + lane] + bufA[(c0 + i) * 64 + lane];
        #pragma unroll
        for (int e = 0; e < 8; ++e) {
            const float* Pr = proj_w + (wu * 8 + e) * CC + c0;   // SGPR base
            #pragma unroll
            for (int i = 0; i < 16; ++i)
                y[e] = fmaf(Pr[i], vv[i], y[e]);
        }
    }
    const size_t ob = (size_t)(b * CC + wu * 8) * HWW + hw0 + lane;
    #pragma unroll
    for (int e = 0; e < 8; ++e)
        out[ob + (size_t)e * HWW] = y[e];
}

extern "C" void kernel_launch(void* const* d_in, const int* in_sizes, int n_in,
                              void* d_out, int out_size, void* d_ws, size_t ws_size,
                              hipStream_t stream) {
    const float* x      = (const float*)d_in[0];
    const float* pe     = (const float*)d_in[1];
    const float* nw     = (const float*)d_in[2];
    const float* nb     = (const float*)d_in[3];
    const float* qkv_w  = (const float*)d_in[4];
    const float* proj_w = (const float*)d_in[5];
    float* out = (float*)d_out;
    float* ws  = (float*)d_ws;

    // no memset needed: stats writes per-block partials non-atomically
    stats_kernel<<<4096, 256, 0, stream>>>(x, pe, ws + WS_PART);
    finalize_kernel<<<32, 128, 0, stream>>>(pe, nw, nb, ws);
    fused6_kernel<<<dim3(HWW / 64, BB), 1024, 0, stream>>>(x, ws, qkv_w, proj_w, out);
}

// Round 7
// 413.931 us; speedup vs baseline: 3.3240x; 1.1394x over previous
//
#include <hip/hip_runtime.h>
#include <math.h>

#define BB 4
#define TT 8
#define CC 128
#define HWW 9216            // 96*96
#define NPG 1179648.0f      // C*H*W per (b,t) group
#define EPS 1e-5f
#define SCALE 0.17677669529663687f    // 1/sqrt(32)
#define SCALE2 0.2550181765195206f    // SCALE * log2(e)

// ws layout in floats: part[4096*2] | A[32][128] | B[32][128]
#define WS_PART 0
#define WS_A    8192
#define WS_B    12288

typedef __attribute__((ext_vector_type(4))) float f32x4;

// stats: one block per (g, c) row; non-atomic per-block partial stores (R6-proven).
__global__ __launch_bounds__(256) void stats_kernel(
    const float* __restrict__ x, const float* __restrict__ pe,
    float* __restrict__ part)
{
    const int bid = blockIdx.x;              // 4096 = 32 g x 128 c
    const int g = bid >> 7, c = bid & 127;
    const int t = g & 7;
    const int tid = threadIdx.x;
    const float pec = pe[t * CC + c];
    const float4* row = (const float4*)(x + ((size_t)g * CC + c) * HWW);
    float s1 = 0.f, s2 = 0.f;
    #pragma unroll
    for (int i = 0; i < 9; ++i) {            // 9*256 = 2304 float4 = 9216 floats
        float4 v = row[tid + i * 256];
        float a = v.x + pec, b = v.y + pec, cc2 = v.z + pec, d = v.w + pec;
        s1 += (a + b) + (cc2 + d);
        s2 += (a * a + b * b) + (cc2 * cc2 + d * d);
    }
    for (int off = 32; off; off >>= 1) {
        s1 += __shfl_down(s1, off);
        s2 += __shfl_down(s2, off);
    }
    __shared__ float red[8];
    const int wid = tid >> 6, lane = tid & 63;
    if (lane == 0) { red[wid] = s1; red[4 + wid] = s2; }
    __syncthreads();
    if (tid == 0) {
        part[bid * 2 + 0] = red[0] + red[1] + red[2] + red[3];
        part[bid * 2 + 1] = red[4] + red[5] + red[6] + red[7];
    }
}

// finalize: block g reduces its 128 c-partials (R6-proven).
__global__ __launch_bounds__(128) void finalize_kernel(
    const float* __restrict__ pe, const float* __restrict__ nw,
    const float* __restrict__ nb, float* ws)
{
    const int g = blockIdx.x;
    const int c = threadIdx.x;               // 0..127
    const float* part = ws + WS_PART + g * 256;
    float s1 = part[c * 2 + 0];
    float s2 = part[c * 2 + 1];
    for (int off = 32; off; off >>= 1) {
        s1 += __shfl_down(s1, off);
        s2 += __shfl_down(s2, off);
    }
    __shared__ float r[4];
    const int wid = c >> 6, lane = c & 63;
    if (lane == 0) { r[wid] = s1; r[2 + wid] = s2; }
    __syncthreads();
    const float inv = 1.0f / NPG;
    const float mean = (r[0] + r[1]) * inv;
    const float var  = (r[2] + r[3]) * inv - mean * mean;
    const float rstd = rsqrtf(var + EPS);
    const int t = g & 7;
    const float a = rstd * nw[c];
    ws[WS_A + g * CC + c] = a;
    ws[WS_B + g * CC + c] = (pe[t * CC + c] - mean) * a + nb[c];
}

// fused7 = fused6 structure with FOLD-AT-STAGE: tiles are normalized once in
// registers during staging (a,b preloaded per-row), written pre-folded to LDS.
// Removes the 4x-head-redundant fold from q7/score/xb phases (~1100 FMA/thread).
// Staging role: thread covers row r = tid>>3, floats [8k, 8k+8) of the 64-pos row.
// All barriers plain __syncthreads(); buffer protocol mirrors fused6.
__global__ __launch_bounds__(1024, 4) void fused7_kernel(
    const float* __restrict__ x, const float* __restrict__ ws,
    const float* __restrict__ qkv_w, const float* __restrict__ proj_w,
    float* __restrict__ out)
{
    __shared__ __align__(16) float bufA[CC * 64];
    __shared__ __align__(16) float bufB[CC * 64];

    const int tid  = threadIdx.x;
    const int lane = tid & 63;                  // position
    const int w    = tid >> 6;                  // wave 0..15
    const int wu   = __builtin_amdgcn_readfirstlane(w);
    const int n    = wu >> 2;                   // head
    const int hq   = wu & 3;                    // c-quarter
    const int b    = blockIdx.y;
    const int hw0  = blockIdx.x * 64;

    const int r  = tid >> 3;                    // staging row 0..127
    const int k8 = (tid & 7) * 8;               // staging float offset 0,8,..,56

    // per-row fold constants for all 8 tiles (8 lanes share r -> L1 broadcast)
    float ar[8], br[8];
    #pragma unroll
    for (int t = 0; t < 8; ++t) {
        ar[t] = ws[WS_A + (b * TT + t) * CC + r];
        br[t] = ws[WS_B + (b * TT + t) * CC + r];
    }

    const float* xrow = x + ((size_t)(b * TT) * CC + r) * HWW + hw0 + k8;

    f32x4 rg0, rg1;                             // staging registers (tile in flight)
    auto ldtile = [&](int t) {                  // issue 32B of tile t -> regs
        const float* p = xrow + (size_t)t * CC * HWW;
        rg0 = *(const f32x4*)(p);
        rg1 = *(const f32x4*)(p + 4);
    };
    auto wrtile = [&](float a, float bb2, float* dst) {  // fold + ds_write_b128 x2
        f32x4 f0, f1;
        f0.x = fmaf(rg0.x, a, bb2); f0.y = fmaf(rg0.y, a, bb2);
        f0.z = fmaf(rg0.z, a, bb2); f0.w = fmaf(rg0.w, a, bb2);
        f1.x = fmaf(rg1.x, a, bb2); f1.y = fmaf(rg1.y, a, bb2);
        f1.z = fmaf(rg1.z, a, bb2); f1.w = fmaf(rg1.w, a, bb2);
        *(f32x4*)&dst[r * 64 + k8]     = f0;
        *(f32x4*)&dst[r * 64 + k8 + 4] = f1;
    };

    float u[32];
    // score over pre-folded tile: sum_j u[j] * buf[hq*32+j][lane]
    auto score = [&](const float* buf) {
        float s0 = 0.f, s1 = 0.f, s2 = 0.f, s3 = 0.f;
        #pragma unroll
        for (int j = 0; j < 32; j += 4) {
            s0 = fmaf(u[j + 0], buf[(hq * 32 + j + 0) * 64 + lane], s0);
            s1 = fmaf(u[j + 1], buf[(hq * 32 + j + 1) * 64 + lane], s1);
            s2 = fmaf(u[j + 2], buf[(hq * 32 + j + 2) * 64 + lane], s2);
            s3 = fmaf(u[j + 3], buf[(hq * 32 + j + 3) * 64 + lane], s3);
        }
        return (s0 + s1) + (s2 + s3);
    };

    // ---- prologue: tile 7 folded into bufA ----
    ldtile(7);
    wrtile(ar[7], br[7], bufA);
    __syncthreads();                            // tile7 ready (folded)

    // ---- q7 = Wq_n xn7 (8 d-rows per wave) from folded bufA -> bufB ----
    {
        const float* Wq = qkv_w + (n * 32 + hq * 8) * CC;
        float q7[8] = {0.f,0.f,0.f,0.f,0.f,0.f,0.f,0.f};
        for (int c0 = 0; c0 < CC; c0 += 8) {
            float xv[8];
            #pragma unroll
            for (int i = 0; i < 8; ++i)
                xv[i] = bufA[(c0 + i) * 64 + lane];
            #pragma unroll
            for (int d = 0; d < 8; ++d) {
                #pragma unroll
                for (int i = 0; i < 8; ++i)
                    q7[d] = fmaf(Wq[d * CC + c0 + i], xv[i], q7[d]);
            }
        }
        #pragma unroll
        for (int d = 0; d < 8; ++d)
            bufB[(n * 32 + hq * 8 + d) * 64 + lane] = q7[d];
    }
    __syncthreads();                            // q7 visible

    ldtile(0);                                  // t0 loads fly under u-compute

    // ---- u[32] = (Wk_n^T q7) slice hq*32.. ----
    #pragma unroll
    for (int j = 0; j < 32; ++j) u[j] = 0.f;
    {
        const float* Wk = qkv_w + (CC + n * 32) * CC + hq * 32;
        for (int d = 0; d < 32; ++d) {
            const float qv = bufB[(n * 32 + d) * 64 + lane];
            #pragma unroll
            for (int j = 0; j < 32; ++j)
                u[j] = fmaf(Wk[d * CC + j], qv, u[j]);
        }
    }
    __syncthreads();                            // q7 reads done; bufB free

    // ---- phase A: scores from folded tiles, 1 barrier/tile ----
    float ps[8];
    wrtile(ar[0], br[0], bufB);                 // t0 folded into bufB
    ps[7] = score(bufA);
    ldtile(1);
    __syncthreads();                            // t0 visible; bufA (t7) dead

    #pragma unroll
    for (int t = 0; t < 7; ++t) {
        const float* curb = (t & 1) ? bufA : bufB;
        float* othb = (t & 1) ? bufB : bufA;
        if (t < 6) {
            if (t == 0) wrtile(ar[1], br[1], othb);
            if (t == 1) wrtile(ar[2], br[2], othb);
            if (t == 2) wrtile(ar[3], br[3], othb);
            if (t == 3) wrtile(ar[4], br[4], othb);
            if (t == 4) wrtile(ar[5], br[5], othb);
            if (t == 5) wrtile(ar[6], br[6], othb);
        }
        if (t < 5) ldtile(t + 2);
        ps[t] = score(curb);
        __syncthreads();                        // next tile visible; curb dead next iter
    }

    // ---- exchange via bufA rows (both bufs dead now) + exact softmax ----
    ldtile(0);                                  // phase-B t0 prefetch
    #pragma unroll
    for (int t = 0; t < 8; ++t)
        bufA[(wu * 8 + t) * 64 + lane] = ps[t];
    __syncthreads();

    float wt[8];
    {
        float sreg[8];
        #pragma unroll
        for (int t = 0; t < 8; ++t)
            sreg[t] = (bufA[((n * 4 + 0) * 8 + t) * 64 + lane] +
                       bufA[((n * 4 + 1) * 8 + t) * 64 + lane]) +
                      (bufA[((n * 4 + 2) * 8 + t) * 64 + lane] +
                       bufA[((n * 4 + 3) * 8 + t) * 64 + lane]);
        float m = fmaxf(fmaxf(fmaxf(sreg[0], sreg[1]), fmaxf(sreg[2], sreg[3])),
                        fmaxf(fmaxf(sreg[4], sreg[5]), fmaxf(sreg[6], sreg[7])));
        float l = 0.f;
        #pragma unroll
        for (int t = 0; t < 8; ++t) { wt[t] = exp2f((sreg[t] - m) * SCALE2); l += wt[t]; }
        const float invl = 1.0f / l;
        #pragma unroll
        for (int t = 0; t < 8; ++t) wt[t] *= invl;
    }
    __syncthreads();                            // sreg reads done; bufA free

    // ---- phase B: restage all 8 folded tiles (L2-hot), xb += wt*xnf ----
    // write target wb(t): t even -> bufA, t odd -> bufB; consume(t-1) from wb(t-1)
    float xb[32];
    #pragma unroll
    for (int j = 0; j < 32; ++j) xb[j] = 0.f;
    #pragma unroll
    for (int t = 0; t < 8; ++t) {
        float* wb = (t & 1) ? bufB : bufA;
        {
            if (t == 0) wrtile(ar[0], br[0], wb);
            if (t == 1) wrtile(ar[1], br[1], wb);
            if (t == 2) wrtile(ar[2], br[2], wb);
            if (t == 3) wrtile(ar[3], br[3], wb);
            if (t == 4) wrtile(ar[4], br[4], wb);
            if (t == 5) wrtile(ar[5], br[5], wb);
            if (t == 6) wrtile(ar[6], br[6], wb);
            if (t == 7) wrtile(ar[7], br[7], wb);
        }
        if (t < 7) ldtile(t + 1);
        if (t >= 1) {
            const float* rb = (t & 1) ? bufA : bufB;   // wb(t-1)
            const float wc = wt[t - 1];
            #pragma unroll
            for (int j = 0; j < 32; ++j)
                xb[j] = fmaf(rb[(hq * 32 + j) * 64 + lane], wc, xb[j]);
        }
        __syncthreads();                        // wb(t) visible; wb(t-1) dead
    }
    {                                           // tail: consume t7 from bufB
        const float wc = wt[7];
        #pragma unroll
        for (int j = 0; j < 32; ++j)
            xb[j] = fmaf(bufB[(hq * 32 + j) * 64 + lane], wc, xb[j]);
    }
    __syncthreads();                            // all tile reads done; bufs free

    // ---- v: all waves compute quarter partials; pairwise tree (fused6-proven) ----
    // v01 (hq0+hq1) accumulates in bufB rows; v23 in bufA rows.
    {
        const float* Wv = qkv_w + (2 * CC + n * 32) * CC + hq * 32;
        float vprev[8];
        #pragma unroll
        for (int gi = 0; gi < 4; ++gi) {
            float vp[8];
            #pragma unroll
            for (int d = 0; d < 8; ++d) {
                float s0 = 0.f, s1 = 0.f, s2 = 0.f, s3 = 0.f;
                const float* Wr = Wv + (gi * 8 + d) * CC;
                #pragma unroll
                for (int c = 0; c < 32; c += 4) {
                    s0 = fmaf(Wr[c + 0], xb[c + 0], s0);
                    s1 = fmaf(Wr[c + 1], xb[c + 1], s1);
                    s2 = fmaf(Wr[c + 2], xb[c + 2], s2);
                    s3 = fmaf(Wr[c + 3], xb[c + 3], s3);
                }
                vp[d] = (s0 + s1) + (s2 + s3);
            }
            if (hq == 1) {
                #pragma unroll
                for (int d = 0; d < 8; ++d)
                    bufB[(n * 32 + gi * 8 + d) * 64 + lane] = vp[d];
            }
            if (hq == 3) {
                #pragma unroll
                for (int d = 0; d < 8; ++d)
                    bufA[(n * 32 + gi * 8 + d) * 64 + lane] = vp[d];
            }
            if (gi > 0) {
                if (hq == 0) {
                    #pragma unroll
                    for (int d = 0; d < 8; ++d)
                        bufB[(n * 32 + (gi - 1) * 8 + d) * 64 + lane] += vprev[d];
                }
                if (hq == 2) {
                    #pragma unroll
                    for (int d = 0; d < 8; ++d)
                        bufA[(n * 32 + (gi - 1) * 8 + d) * 64 + lane] += vprev[d];
                }
            }
            #pragma unroll
            for (int d = 0; d < 8; ++d) vprev[d] = vp[d];
            __syncthreads();
        }
        if (hq == 0) {
            #pragma unroll
            for (int d = 0; d < 8; ++d)
                bufB[(n * 32 + 24 + d) * 64 + lane] += vprev[d];
        }
        if (hq == 2) {
            #pragma unroll
            for (int d = 0; d < 8; ++d)
                bufA[(n * 32 + 24 + d) * 64 + lane] += vprev[d];
        }
    }
    __syncthreads();                            // v01/v23 complete

    // ---- y[e] = sum_c P[e][c] * (v01[c]+v23[c]), e-slice per wave ----
    float y[8];
    #pragma unroll
    for (int e = 0; e < 8; ++e) y[e] = 0.f;
    for (int c0 = 0; c0 < CC; c0 += 16) {
        float vv[16];
        #pragma unroll
        for (int i = 0; i < 16; ++i)
            vv[i] = bufB[(c0 + i) * 64 + lane] + bufA[(c0 + i) * 64 + lane];
        #pragma unroll
        for (int e = 0; e < 8; ++e) {
            const float* Pr = proj_w + (wu * 8 + e) * CC + c0;   // SGPR base
            #pragma unroll
            for (int i = 0; i < 16; ++i)
                y[e] = fmaf(Pr[i], vv[i], y[e]);
        }
    }
    const size_t ob = (size_t)(b * CC + wu * 8) * HWW + hw0 + lane;
    #pragma unroll
    for (int e = 0; e < 8; ++e)
        out[ob + (size_t)e * HWW] = y[e];
}

extern "C" void kernel_launch(void* const* d_in, const int* in_sizes, int n_in,
                              void* d_out, int out_size, void* d_ws, size_t ws_size,
                              hipStream_t stream) {
    const float* x      = (const float*)d_in[0];
    const float* pe     = (const float*)d_in[1];
    const float* nw     = (const float*)d_in[2];
    const float* nb     = (const float*)d_in[3];
    const float* qkv_w  = (const float*)d_in[4];
    const float* proj_w = (const float*)d_in[5];
    float* out = (float*)d_out;
    float* ws  = (float*)d_ws;

    stats_kernel<<<4096, 256, 0, stream>>>(x, pe, ws + WS_PART);
    finalize_kernel<<<32, 128, 0, stream>>>(pe, nw, nb, ws);
    fused7_kernel<<<dim3(HWW / 64, BB), 1024, 0, stream>>>(x, ws, qkv_w, proj_w, out);
}